// Round 11
// baseline (118.002 us; speedup 1.0000x reference)
//
#include <hip/hip_runtime.h>

#define D 512      // view dim / d_out
#define B 4096     // batch
#define R 32       // TT rank
#define AB 1024    // R*R rows of reshaped core GEMM

typedef unsigned short ushort_t;
typedef __attribute__((ext_vector_type(8))) short bf16x8;
typedef __attribute__((ext_vector_type(4))) float f32x4;

__device__ __forceinline__ ushort_t f2bf(float f) {
  uint32_t u = __builtin_bit_cast(uint32_t, f);
  u = (u + 0x7FFFu + ((u >> 16) & 1u)) >> 16;   // RNE
  return (ushort_t)u;
}
__device__ __forceinline__ float bf2f(ushort_t h) {
  uint32_t u = ((uint32_t)h) << 16;
  return __builtin_bit_cast(float, u);
}
__device__ __forceinline__ void gload_lds16(const void* g, void* lds) {
  __builtin_amdgcn_global_load_lds(
      (const __attribute__((address_space(1))) unsigned int*)g,
      (__attribute__((address_space(3))) unsigned int*)lds, 16, 0, 0);
}

// ---------------------------------------------------------------------------
// K1: prep — one flat-grid kernel (identical to R8-measured):
//   bid <  1536 : transpose X_v fp32 [d][n] -> Xt bf16 [v][n][d]  (v = bid/512)
//   1536..1599  : pack core1/core2 [a][d][b] -> Apack[j][a*32+b][d]
//   1600..1607  : pack core3 [c][d] -> Apack3[128][512] (rows 32..127 zeroed)
// ---------------------------------------------------------------------------
__global__ __launch_bounds__(256) void prep(
    const float* __restrict__ X0, const float* __restrict__ X1,
    const float* __restrict__ X2, const float* __restrict__ c1,
    const float* __restrict__ c2, const float* __restrict__ c3,
    ushort_t* __restrict__ Xt, ushort_t* __restrict__ Apack,
    ushort_t* __restrict__ Apack3)
{
  __shared__ __align__(16) char smem[33280];
  const int bid = blockIdx.x, tid = threadIdx.x;

  if (bid < 1536) {
    // ---- transpose: 64x64 tile ----
    float (*T)[65] = (float(*)[65])smem;          // [64][65]
    const int v = bid / 512, tile = bid % 512;
    const float* __restrict__ X = (v == 0) ? X0 : ((v == 1) ? X1 : X2);
    ushort_t* __restrict__ O = Xt + (size_t)v * B * D;
    const int n0 = (tile & 63) * 64, d0 = (tile >> 6) * 64;
#pragma unroll
    for (int i = 0; i < 16; ++i) {
      int e = i * 256 + tid;
      T[e >> 6][e & 63] = X[(size_t)(d0 + (e >> 6)) * B + n0 + (e & 63)];
    }
    __syncthreads();
#pragma unroll
    for (int i = 0; i < 2; ++i) {
      int ch = i * 256 + tid;                // 512 chunks
      int nr = ch >> 3, dc = (ch & 7) * 8;
      ushort_t w[8];
#pragma unroll
      for (int q = 0; q < 8; ++q) w[q] = f2bf(T[dc + q][nr]);
      *(bf16x8*)&O[(size_t)(n0 + nr) * D + d0 + dc] = *(bf16x8*)w;
    }
  } else if (bid < 1600) {
    // ---- pack core1/core2 ----
    ushort_t (*T)[D + 8] = (ushort_t(*)[D + 8])smem;   // [32][520]
    const int ja = bid - 1536, j = ja >> 5, a = ja & 31;
    const float* __restrict__ c = j ? c2 : c1;
#pragma unroll
    for (int i = 0; i < 64; ++i) {
      int e = i * 256 + tid;                 // e = d*32 + b, coalesced source
      T[e & 31][e >> 5] = f2bf(c[(size_t)a * (D * R) + e]);
    }
    __syncthreads();
#pragma unroll
    for (int i = 0; i < 8; ++i) {
      int ch = i * 256 + tid;                // 2048 16B chunks
      int b = ch >> 6, off = (ch & 63) * 8;
      ushort_t w[8];
#pragma unroll
      for (int q = 0; q < 8; ++q) w[q] = T[b][off + q];
      *(bf16x8*)&Apack[((size_t)j * AB + a * 32 + b) * D + off] = *(bf16x8*)w;
    }
  } else {
    // ---- pack core3: 16 rows per block ----
    const int r0 = (bid - 1600) * 16;
#pragma unroll
    for (int i = 0; i < 4; ++i) {
      int ch = i * 256 + tid;                // 1024 8-elem chunks = 16x512
      int rr = r0 + (ch >> 6), off = (ch & 63) * 8;
      ushort_t w[8];
      if (rr < R) {
#pragma unroll
        for (int q = 0; q < 8; ++q) w[q] = f2bf(c3[(size_t)rr * D + off + q]);
      } else {
#pragma unroll
        for (int q = 0; q < 8; ++q) w[q] = 0;
      }
      *(bf16x8*)&Apack3[(size_t)rr * D + off] = *(bf16x8*)w;
    }
  }
}

// ---------------------------------------------------------------------------
// K2: MFMA GEMM (identical to R8-measured), 3 "views", XCD-chunked swizzle.
//   wgid<512 : Mt_j[n][row] = sum_d Xt_j[n][d] * Apack_j[row][d], j=wgid>>8
//   wgid>=512: Mt2[n][c]    = sum_d Xt_2[n][d] * Apack3[c][d]   (32 blocks)
// 128x128 tile, BK=32, 4 waves, dbuf global_load_lds, XOR-swizzled LDS,
// LDS-staged epilogue for coalesced [n][row] stores.
// ---------------------------------------------------------------------------
__global__ __launch_bounds__(256) void gemm_mfma(
    const ushort_t* __restrict__ Apack, const ushort_t* __restrict__ Apack3,
    const ushort_t* __restrict__ Xt, ushort_t* __restrict__ Mt,
    ushort_t* __restrict__ Mt2)
{
  __shared__ __align__(16) ushort_t smem[17408];   // 34.8 KB
  ushort_t* As0 = smem;            // Xt tile buf0: [128 n][32 k] swizzled
  ushort_t* As1 = smem + 4096;
  ushort_t* Bs0 = smem + 8192;     // core tile
  ushort_t* Bs1 = smem + 12288;

  const int bid0 = blockIdx.x;
  const int bid = ((bid0 & 7) * 68) + (bid0 >> 3);

  int j, rb, nb, ldc;
  const ushort_t *Ag, *Bg;
  ushort_t* C;
  if (bid < 512) {
    j = bid >> 8; int w = bid & 255; nb = w >> 3; rb = w & 7;   // nb-major
    Ag = Xt + (size_t)j * B * D;
    Bg = Apack + (size_t)j * AB * D;
    C  = Mt + (size_t)j * B * AB;  ldc = AB;
  } else {
    j = 2; rb = 0; nb = bid - 512;
    Ag = Xt + (size_t)2 * B * D;
    Bg = Apack3;
    C  = Mt2;  ldc = 128;
  }

  const int tid = threadIdx.x;
  const int lane = tid & 63, wid = tid >> 6;
  const int wr = wid >> 1, wc = wid & 1;
  const int nBase = nb * 128;   // over B=4096
  const int rBase = rb * 128;   // over row dim

  const int t0 = wid * 128 + lane, t1 = t0 + 64;
  const int r0 = t0 >> 2, u0 = (t0 & 3) ^ (r0 & 3);
  const int r1 = t1 >> 2, u1 = (t1 & 3) ^ (r1 & 3);
  const ushort_t* gA0 = Ag + (size_t)(nBase + r0) * D + u0 * 8;
  const ushort_t* gA1 = Ag + (size_t)(nBase + r1) * D + u1 * 8;
  const ushort_t* gB0 = Bg + (size_t)(rBase + r0) * D + u0 * 8;
  const ushort_t* gB1 = Bg + (size_t)(rBase + r1) * D + u1 * 8;
  const int lq0 = wid * 1024, lq1 = wid * 1024 + 512;   // element offsets

  int aoff[4], boff[4];
#pragma unroll
  for (int m = 0; m < 4; ++m) {
    int row = wr * 64 + m * 16 + (lane & 15);
    aoff[m] = row * 32 + (((lane >> 4) ^ (row & 3)) * 8);
  }
#pragma unroll
  for (int n = 0; n < 4; ++n) {
    int col = wc * 64 + n * 16 + (lane & 15);
    boff[n] = col * 32 + (((lane >> 4) ^ (col & 3)) * 8);
  }

  f32x4 acc[4][4] = {};

  auto stage = [&](ushort_t* Asb, ushort_t* Bsb, int k0) {
    gload_lds16(gA0 + k0, Asb + lq0);
    gload_lds16(gA1 + k0, Asb + lq1);
    gload_lds16(gB0 + k0, Bsb + lq0);
    gload_lds16(gB1 + k0, Bsb + lq1);
  };
  auto compute = [&](const ushort_t* Asb, const ushort_t* Bsb) {
    bf16x8 a[4], b[4];
#pragma unroll
    for (int m = 0; m < 4; ++m) a[m] = *(const bf16x8*)&Asb[aoff[m]];
#pragma unroll
    for (int n = 0; n < 4; ++n) b[n] = *(const bf16x8*)&Bsb[boff[n]];
#pragma unroll
    for (int m = 0; m < 4; ++m)
#pragma unroll
      for (int n = 0; n < 4; ++n)
        acc[m][n] = __builtin_amdgcn_mfma_f32_16x16x32_bf16(a[m], b[n], acc[m][n], 0, 0, 0);
  };

  stage(As0, Bs0, 0);
  __syncthreads();
#pragma unroll 1
  for (int kp = 0; kp < 8; ++kp) {
    stage(As1, Bs1, kp * 64 + 32);        // prefetch odd tile
    compute(As0, Bs0);
    __syncthreads();
    if (kp < 7) stage(As0, Bs0, kp * 64 + 64);  // prefetch next even tile
    compute(As1, Bs1);
    __syncthreads();
  }

  // epilogue: acc -> LDS tile T[128 n][128 row] (pad 8) -> coalesced stores
#define TLD 136
  ushort_t* T = smem;
  const int qn = (lane >> 4) << 2;
#pragma unroll
  for (int m = 0; m < 4; ++m)
#pragma unroll
    for (int nn = 0; nn < 4; ++nn) {
      int nl = wr * 64 + m * 16 + qn;
      int rl = wc * 64 + nn * 16 + (lane & 15);
#pragma unroll
      for (int r = 0; r < 4; ++r)
        T[(nl + r) * TLD + rl] = f2bf(acc[m][nn][r]);
    }
  __syncthreads();
#pragma unroll
  for (int i = 0; i < 8; ++i) {
    int nl = i * 16 + (tid >> 4);
    int rl = (tid & 15) * 8;
    bf16x8 v = *(const bf16x8*)&T[nl * TLD + rl];
    *(bf16x8*)&C[(size_t)(nBase + nl) * ldc + rBase + rl] = v;
  }
}

// ---------------------------------------------------------------------------
// K3: finish — fused chain + zgemm, block-local (16 samples per block).
//   chain: per wave 2 samples x 2 iters (8/wave-pair structure as measured);
//          z[a] written to LDS zs[a][n_local] instead of global.
//   zgemm: Z[d][n] = sum_a core0[d][a] * zs[a][n_local], d split over ty.
// ---------------------------------------------------------------------------
__global__ __launch_bounds__(256) void finish(
    const ushort_t* __restrict__ Mt, const ushort_t* __restrict__ Mt2,
    const float* __restrict__ core0, float* __restrict__ out)
{
  __shared__ float zs[R][20];     // [a][n_local], pad 20
  __shared__ float ts[4][R];
  const int tid = threadIdx.x;
  const int lane = tid & 63, w = tid >> 6;
  const int h = lane & 1, g = lane >> 1;
  const ushort_t* __restrict__ Mt0 = Mt;                    // [n][1024]
  const ushort_t* __restrict__ Mt1 = Mt + (size_t)B * AB;
  const int n0 = blockIdx.x * 16;

  // ---- chain: 16 samples, 4 waves x 2 samples x 2 iterations ----
#pragma unroll
  for (int it = 0; it < 2; ++it) {
#pragma unroll
    for (int s = 0; s < 2; ++s) {
      const int nl = it * 8 + w * 2 + s;
      const int n = n0 + nl;
      const size_t rowbase = (size_t)n * AB + lane * 16;

      bf16x8 m2a = *(const bf16x8*)&Mt2[(size_t)n * 128 + h * 16];
      bf16x8 m2b = *(const bf16x8*)&Mt2[(size_t)n * 128 + h * 16 + 8];
      bf16x8 m1a = *(const bf16x8*)&Mt1[rowbase];
      bf16x8 m1b = *(const bf16x8*)&Mt1[rowbase + 8];
      bf16x8 m0a = *(const bf16x8*)&Mt0[rowbase];
      bf16x8 m0b = *(const bf16x8*)&Mt0[rowbase + 8];

      float pt = 0.f;
#pragma unroll
      for (int k = 0; k < 8; ++k) pt += bf2f((ushort_t)m1a[k]) * bf2f((ushort_t)m2a[k]);
#pragma unroll
      for (int k = 0; k < 8; ++k) pt += bf2f((ushort_t)m1b[k]) * bf2f((ushort_t)m2b[k]);
      pt += __shfl_xor(pt, 1, 64);
      if (h == 0) ts[w][g] = pt;          // t[b] complete, b = g

      float pz = 0.f;
#pragma unroll
      for (int k = 0; k < 8; ++k) pz += bf2f((ushort_t)m0a[k]) * ts[w][h * 16 + k];
#pragma unroll
      for (int k = 0; k < 8; ++k) pz += bf2f((ushort_t)m0b[k]) * ts[w][h * 16 + 8 + k];
      pz += __shfl_xor(pz, 1, 64);
      if (h == 0) zs[g][nl] = pz;         // z[a], a = g, LDS-resident
    }
  }
  __syncthreads();

  // ---- zgemm: tx = n_local (16), ty = d-group (16 x 32 rows) ----
  const int tx = tid & 15, ty = tid >> 4;
  float zcol[R];
#pragma unroll
  for (int a = 0; a < R; ++a) zcol[a] = zs[a][tx];
#pragma unroll 4
  for (int dd = 0; dd < 32; ++dd) {
    const int d = ty * 32 + dd;
    float acc = 0.f;
#pragma unroll
    for (int a4 = 0; a4 < 8; ++a4) {
      float4 c = *(const float4*)&core0[(size_t)d * R + a4 * 4];
      acc += c.x * zcol[a4 * 4 + 0] + c.y * zcol[a4 * 4 + 1] +
             c.z * zcol[a4 * 4 + 2] + c.w * zcol[a4 * 4 + 3];
    }
    out[(size_t)d * B + n0 + tx] = acc;
  }
}

// ---------------------------------------------------------------------------
extern "C" void kernel_launch(void* const* d_in, const int* in_sizes, int n_in,
                              void* d_out, int out_size, void* d_ws, size_t ws_size,
                              hipStream_t stream)
{
  const float* X0    = (const float*)d_in[0];
  const float* X1    = (const float*)d_in[1];
  const float* X2    = (const float*)d_in[2];
  const float* core0 = (const float*)d_in[3];
  const float* core1 = (const float*)d_in[4];
  const float* core2 = (const float*)d_in[5];
  const float* core3 = (const float*)d_in[6];
  float* out = (float*)d_out;

  char* ws = (char*)d_ws;
  ushort_t* Apack  = (ushort_t*)(ws);                       //  2 MiB @ 0
  ushort_t* Apack3 = (ushort_t*)(ws + (2u  << 20));         //  128 KiB
  ushort_t* Xt     = (ushort_t*)(ws + (4u  << 20));         //  12 MiB (3 views)
  ushort_t* Mt     = (ushort_t*)(ws + (16u << 20));         //  16 MiB
  ushort_t* Mt2    = (ushort_t*)(ws + (32u << 20));         //   1 MiB

  hipLaunchKernelGGL(prep, dim3(1608), dim3(256), 0, stream,
                     X0, X1, X2, core1, core2, core3, Xt, Apack, Apack3);
  hipLaunchKernelGGL(gemm_mfma, dim3(544), dim3(256), 0, stream,
                     Apack, Apack3, Xt, Mt, Mt2);
  hipLaunchKernelGGL(finish, dim3(256), dim3(256), 0, stream,
                     Mt, Mt2, core0, out);
}